// Round 3
// baseline (392.348 us; speedup 1.0000x reference)
//
#include <hip/hip_runtime.h>
#include <hip/hip_cooperative_groups.h>
#include <math.h>

namespace cg = cooperative_groups;

#define N_PROT 50000
#define N_SUB  2000
#define D_PROT 256
#define D_SUB  256
#define D_PROJ 128
#define KW     16
#define N_INT  64
#define NWIN   (N_PROT - KW + 1)

// output layout (floats)
#define OUT_SUB (N_PROT * D_PROT)                 // 12,800,000
#define OUT_IDX (OUT_SUB + N_SUB * D_SUB)         // 13,312,000

// ws layout (floats)
#define WS_PACK  0                                // [0..1] packed argmax u64
#define WS_REACT 2                                // [2..129] reaction
#define WS_U1    132                              // fallback path only
#define WS_U2    388                              // fallback path only
#define WS_G     644                              // g[N_PROT] (no constant term)
#define WS_P     (WS_G + N_PROT)                  // P[N_PROT] (no constant term)

#define PB 782                                    // prot blocks: 782*64 >= 50000 rows
#define SB 8                                      // sub-copy blocks
#define NBLK (PB + SB + 1)                        // +1 reaction/init block
#define WBLK ((NWIN + 255) / 256)                 // 196 window blocks (reuse low ids)

// =================== single cooperative kernel ===============================
__global__ __launch_bounds__(256, 4) void k_all(
    const float* __restrict__ prot, const float* __restrict__ sub_node,
    const int* __restrict__ int_index, const float* __restrict__ Wp,
    const float* __restrict__ bp, const float* __restrict__ Ws,
    const float* __restrict__ bs, const float* __restrict__ wa,
    const float* __restrict__ sub_out, const float* __restrict__ prot_out,
    float* __restrict__ out, float* __restrict__ ws) {
  cg::grid_group grid = cg::this_grid();
  const int tid = threadIdx.x, lane = tid & 63, wave = tid >> 6;
  const int b = blockIdx.x;

  __shared__ float su1[D_PROT], su2[D_PROT];     // per-block u1,u2
  __shared__ float swa[D_PROJ];
  __shared__ float sg[256 + KW], sp[256 + KW];   // phase 2
  __shared__ unsigned long long wred[4];
  // phase 3 (block 0 only)
  __shared__ float aprot[KW][D_PROT];
  __shared__ float proj16[KW][D_PROJ];
  __shared__ float attn[KW];
  __shared__ float ts[D_PROJ];
  __shared__ float pdelta[D_PROT], sdelta[D_SUB];
  __shared__ int   sidx[N_INT];

  // ---------------- phase 1 --------------------------------------------------
  if (b < PB) {
    // per-block u1 = Wp@w1, u2 = Wp@ones (Wp is 128 KB, L2/L3-resident)
    if (tid < D_PROJ) swa[tid] = wa[tid];
    __syncthreads();
    {
      float s1 = 0.f, s2 = 0.f;
      const float4* wrow = (const float4*)&Wp[tid * D_PROJ];
      #pragma unroll 8
      for (int j4 = 0; j4 < D_PROJ / 4; ++j4) {
        float4 w = wrow[j4];
        float4 a = *(const float4*)&swa[j4 * 4];
        s1 = fmaf(w.x, a.x, fmaf(w.y, a.y, fmaf(w.z, a.z, fmaf(w.w, a.w, s1))));
        s2 += w.x + w.y + w.z + w.w;
      }
      su1[tid] = s1; su2[tid] = s2;
    }
    __syncthreads();
    const float4 c1 = *(const float4*)&su1[lane * 4];
    const float4 c2 = *(const float4*)&su2[lane * 4];
    const int rbase = b * 64 + wave * 16;
    if (rbase + 16 <= N_PROT) {
      #pragma unroll 4
      for (int i = 0; i < 16; ++i) {
        const int r = rbase + i;
        const float4 av = *(const float4*)&prot[r * D_PROT + lane * 4];
        *(float4*)&out[r * D_PROT + lane * 4] = av;
        float g = av.x * c1.x + av.y * c1.y + av.z * c1.z + av.w * c1.w;
        float p = av.x * c2.x + av.y * c2.y + av.z * c2.z + av.w * c2.w;
        #pragma unroll
        for (int off = 32; off > 0; off >>= 1) {
          g += __shfl_xor(g, off, 64);
          p += __shfl_xor(p, off, 64);
        }
        if (lane == 0) { ws[WS_G + r] = g; ws[WS_P + r] = p; }
      }
    } else {
      for (int i = 0; i < 16; ++i) {
        const int r = rbase + i;
        if (r >= N_PROT) break;
        const float4 av = *(const float4*)&prot[r * D_PROT + lane * 4];
        *(float4*)&out[r * D_PROT + lane * 4] = av;
        float g = av.x * c1.x + av.y * c1.y + av.z * c1.z + av.w * c1.w;
        float p = av.x * c2.x + av.y * c2.y + av.z * c2.z + av.w * c2.w;
        for (int off = 32; off > 0; off >>= 1) {
          g += __shfl_xor(g, off, 64);
          p += __shfl_xor(p, off, 64);
        }
        if (lane == 0) { ws[WS_G + r] = g; ws[WS_P + r] = p; }
      }
    }
  } else if (b < PB + SB) {
    const int sb = b - PB;
    #pragma unroll 4
    for (int i = tid; i < 16000; i += 256) {
      const int gi = sb * 16000 + i;
      *(float4*)&out[OUT_SUB + gi * 4] = *(const float4*)&sub_node[gi * 4];
    }
    if (sb == 0 && tid < N_INT) out[OUT_IDX + tid] = (float)int_index[tid];
  } else {
    // reaction + argmax init
    __shared__ int   ridx[N_INT];
    __shared__ float ssum[D_SUB];
    if (tid < N_INT) ridx[tid] = int_index[tid];
    __syncthreads();
    float acc = 0.f;
    #pragma unroll 8
    for (int i = 0; i < N_INT; ++i) acc += sub_node[ridx[i] * D_SUB + tid];
    ssum[tid] = acc;
    __syncthreads();
    if (tid < D_PROJ) {
      float r = 64.0f * bs[tid];
      #pragma unroll 8
      for (int d = 0; d < D_SUB; ++d) r = fmaf(ssum[d], Ws[d * D_PROJ + tid], r);
      ws[WS_REACT + tid] = r;
    }
    if (tid == 0) *((unsigned long long*)ws) = 0ull;
  }

  grid.sync();

  // ---------------- phase 2: windowed softmax score + argmax -----------------
  if (b < WBLK) {
    const int w0 = b * 256;
    for (int i = tid; i < 256 + KW - 1; i += 256) {
      int idx = w0 + i;
      bool ok = idx < N_PROT;
      sg[i] = ok ? ws[WS_G + idx] : -1e30f;
      sp[i] = ok ? ws[WS_P + idx] : 0.f;
    }
    __syncthreads();
    int w = w0 + tid;
    unsigned long long best = 0ull;
    if (w < NWIN) {
      float m = sg[tid];
      #pragma unroll
      for (int k = 1; k < KW; ++k) m = fmaxf(m, sg[tid + k]);
      float s = 0.f, t = 0.f;
      #pragma unroll
      for (int k = 0; k < KW; ++k) {
        float e = expf(sg[tid + k] - m);
        s += e;
        t = fmaf(e, sp[tid + k], t);
      }
      t /= s;   // + const dropped: argmax-invariant
      unsigned int bb = __float_as_uint(t);
      unsigned int u = bb ^ ((bb & 0x80000000u) ? 0xFFFFFFFFu : 0x80000000u);
      best = ((unsigned long long)u << 32) |
             (unsigned long long)(0xFFFFFFFFu - (unsigned)w);
    }
    #pragma unroll
    for (int off = 32; off > 0; off >>= 1) {
      unsigned long long o = __shfl_xor(best, off, 64);
      if (o > best) best = o;
    }
    if ((tid & 63) == 0) wred[tid >> 6] = best;
    __syncthreads();
    if (tid == 0) {
      unsigned long long b2 = wred[0];
      for (int i = 1; i < 4; ++i) if (wred[i] > b2) b2 = wred[i];
      atomicMax((unsigned long long*)ws, b2);
    }
  }

  grid.sync();

  // ---------------- phase 3: patch (block 0) ---------------------------------
  if (b == 0) {
    unsigned long long pk = *(const unsigned long long*)ws;
    const int wtop = (int)(0xFFFFFFFFu - (unsigned)(pk & 0xFFFFFFFFull));
    if (tid < N_INT) sidx[tid] = int_index[tid];
    for (int i = tid; i < KW * D_PROT; i += 256) {
      int rr = i >> 8, dd = i & 255;
      aprot[rr][dd] = prot[(wtop + rr) * D_PROT + dd];
    }
    __syncthreads();
    // recompute proj (f32, same math as reference) for the 16 window rows
    const int j = tid & 127, half = tid >> 7;
    float accr[8];
    #pragma unroll
    for (int rr = 0; rr < 8; ++rr) accr[rr] = bp[j];
    for (int k = 0; k < D_PROT; ++k) {
      float wv = Wp[k * D_PROJ + j];
      #pragma unroll
      for (int rr = 0; rr < 8; ++rr)
        accr[rr] = fmaf(aprot[half * 8 + rr][k], wv, accr[rr]);
    }
    #pragma unroll
    for (int rr = 0; rr < 8; ++rr) proj16[half * 8 + rr][j] = accr[rr];
    __syncthreads();
    if (tid == 0) {   // softmax over g window (shift-invariant vs ref)
      float m = ws[WS_G + wtop];
      for (int k = 1; k < KW; ++k) m = fmaxf(m, ws[WS_G + wtop + k]);
      float e[KW], s = 0.f;
      for (int k = 0; k < KW; ++k) { e[k] = expf(ws[WS_G + wtop + k] - m); s += e[k]; }
      for (int k = 0; k < KW; ++k) attn[k] = e[k] / s;
    }
    __syncthreads();
    if (tid < D_PROJ) {
      float a = ws[WS_REACT + tid];
      #pragma unroll
      for (int k = 0; k < KW; ++k) a = fmaf(attn[k], proj16[k][tid], a);
      ts[tid] = a;
    }
    __syncthreads();
    {
      float pa = 0.f, sa = 0.f;
      #pragma unroll 8
      for (int jj = 0; jj < D_PROJ; ++jj) {
        float t = ts[jj];
        pa = fmaf(t, prot_out[jj * D_PROT + tid], pa);
        sa = fmaf(t, sub_out[jj * D_SUB + tid], sa);
      }
      pdelta[tid] = pa; sdelta[tid] = sa;
    }
    __syncthreads();
    for (int i = tid; i < KW * D_PROT; i += 256) {
      int rr = i >> 8, dd = i & 255;
      out[(wtop + rr) * D_PROT + dd] = aprot[rr][dd] + pdelta[dd];
    }
    for (int i = 0; i < N_INT; ++i) {   // duplicates: same value, set-safe
      int idx = sidx[i];
      out[OUT_SUB + idx * D_SUB + tid] = sub_node[idx * D_SUB + tid] + sdelta[tid];
    }
  }
}

// =================== fallback 4-kernel path (if coop launch unavailable) =====
__global__ __launch_bounds__(256) void k_prep(
    const float* __restrict__ sub_node, const int* __restrict__ int_index,
    const float* __restrict__ Ws, const float* __restrict__ bs,
    const float* __restrict__ Wp, const float* __restrict__ wa,
    float* __restrict__ ws) {
  const int tid = threadIdx.x;
  if (blockIdx.x == 0) {
    __shared__ int   sidx[N_INT];
    __shared__ float ssum[D_SUB];
    if (tid < N_INT) sidx[tid] = int_index[tid];
    __syncthreads();
    float acc = 0.f;
    #pragma unroll 8
    for (int i = 0; i < N_INT; ++i) acc += sub_node[sidx[i] * D_SUB + tid];
    ssum[tid] = acc;
    __syncthreads();
    if (tid < D_PROJ) {
      float r = 64.0f * bs[tid];
      #pragma unroll 8
      for (int d = 0; d < D_SUB; ++d) r = fmaf(ssum[d], Ws[d * D_PROJ + tid], r);
      ws[WS_REACT + tid] = r;
    }
    if (tid == 0) *((unsigned long long*)ws) = 0ull;
  } else {
    __shared__ float swa[D_PROJ];
    if (tid < D_PROJ) swa[tid] = wa[tid];
    __syncthreads();
    float s1 = 0.f, s2 = 0.f;
    const float4* wrow = (const float4*)&Wp[tid * D_PROJ];
    #pragma unroll 8
    for (int j4 = 0; j4 < D_PROJ / 4; ++j4) {
      float4 w = wrow[j4];
      float4 a = *(const float4*)&swa[j4 * 4];
      s1 = fmaf(w.x, a.x, fmaf(w.y, a.y, fmaf(w.z, a.z, fmaf(w.w, a.w, s1))));
      s2 += w.x + w.y + w.z + w.w;
    }
    ws[WS_U1 + tid] = s1;
    ws[WS_U2 + tid] = s2;
  }
}

__global__ __launch_bounds__(256) void k_rows(
    const float* __restrict__ prot, const float* __restrict__ sub_node,
    const int* __restrict__ int_index, float* __restrict__ out,
    float* __restrict__ ws) {
  const int tid = threadIdx.x, lane = tid & 63, wave = tid >> 6;
  if (blockIdx.x < PB) {
    const float4 c1 = *(const float4*)&ws[WS_U1 + lane * 4];
    const float4 c2 = *(const float4*)&ws[WS_U2 + lane * 4];
    const int rbase = blockIdx.x * 64 + wave * 16;
    for (int i = 0; i < 16; ++i) {
      const int r = rbase + i;
      if (r >= N_PROT) break;
      const float4 av = *(const float4*)&prot[r * D_PROT + lane * 4];
      *(float4*)&out[r * D_PROT + lane * 4] = av;
      float g = av.x * c1.x + av.y * c1.y + av.z * c1.z + av.w * c1.w;
      float p = av.x * c2.x + av.y * c2.y + av.z * c2.z + av.w * c2.w;
      for (int off = 32; off > 0; off >>= 1) {
        g += __shfl_xor(g, off, 64);
        p += __shfl_xor(p, off, 64);
      }
      if (lane == 0) { ws[WS_G + r] = g; ws[WS_P + r] = p; }
    }
  } else {
    const int sb = blockIdx.x - PB;
    for (int i = tid; i < 16000; i += 256) {
      const int gi = sb * 16000 + i;
      *(float4*)&out[OUT_SUB + gi * 4] = *(const float4*)&sub_node[gi * 4];
    }
    if (sb == 0 && tid < N_INT) out[OUT_IDX + tid] = (float)int_index[tid];
  }
}

__global__ __launch_bounds__(256) void k_window(
    const float* __restrict__ ws, unsigned long long* __restrict__ packed) {
  __shared__ float sg[256 + KW], sp[256 + KW];
  __shared__ unsigned long long wred[4];
  const int tid = threadIdx.x;
  const int w0 = blockIdx.x * 256;
  for (int i = tid; i < 256 + KW - 1; i += 256) {
    int idx = w0 + i;
    bool ok = idx < N_PROT;
    sg[i] = ok ? ws[WS_G + idx] : -1e30f;
    sp[i] = ok ? ws[WS_P + idx] : 0.f;
  }
  __syncthreads();
  int w = w0 + tid;
  unsigned long long best = 0ull;
  if (w < NWIN) {
    float m = sg[tid];
    #pragma unroll
    for (int k = 1; k < KW; ++k) m = fmaxf(m, sg[tid + k]);
    float s = 0.f, t = 0.f;
    #pragma unroll
    for (int k = 0; k < KW; ++k) {
      float e = expf(sg[tid + k] - m);
      s += e;
      t = fmaf(e, sp[tid + k], t);
    }
    t /= s;
    unsigned int bb = __float_as_uint(t);
    unsigned int u = bb ^ ((bb & 0x80000000u) ? 0xFFFFFFFFu : 0x80000000u);
    best = ((unsigned long long)u << 32) |
           (unsigned long long)(0xFFFFFFFFu - (unsigned)w);
  }
  #pragma unroll
  for (int off = 32; off > 0; off >>= 1) {
    unsigned long long o = __shfl_xor(best, off, 64);
    if (o > best) best = o;
  }
  if ((tid & 63) == 0) wred[tid >> 6] = best;
  __syncthreads();
  if (tid == 0) {
    unsigned long long b2 = wred[0];
    for (int i = 1; i < 4; ++i) if (wred[i] > b2) b2 = wred[i];
    atomicMax(packed, b2);
  }
}

__global__ __launch_bounds__(256) void k_final(
    const float* __restrict__ prot, const float* __restrict__ sub_node,
    const int* __restrict__ int_index, const float* __restrict__ Wp,
    const float* __restrict__ bp, const float* __restrict__ sub_out,
    const float* __restrict__ prot_out, const float* __restrict__ ws,
    float* __restrict__ out) {
  __shared__ float aprot[KW][D_PROT];
  __shared__ float proj16[KW][D_PROJ];
  __shared__ float attn[KW];
  __shared__ float ts[D_PROJ];
  __shared__ float pdelta[D_PROT], sdelta[D_SUB];
  __shared__ int   sidx[N_INT];
  const int tid = threadIdx.x;
  unsigned long long pk = *(const unsigned long long*)ws;
  const int wtop = (int)(0xFFFFFFFFu - (unsigned)(pk & 0xFFFFFFFFull));
  if (tid < N_INT) sidx[tid] = int_index[tid];
  for (int i = tid; i < KW * D_PROT; i += 256) {
    int rr = i >> 8, dd = i & 255;
    aprot[rr][dd] = prot[(wtop + rr) * D_PROT + dd];
  }
  __syncthreads();
  const int j = tid & 127, half = tid >> 7;
  float accr[8];
  #pragma unroll
  for (int rr = 0; rr < 8; ++rr) accr[rr] = bp[j];
  for (int k = 0; k < D_PROT; ++k) {
    float wv = Wp[k * D_PROJ + j];
    #pragma unroll
    for (int rr = 0; rr < 8; ++rr)
      accr[rr] = fmaf(aprot[half * 8 + rr][k], wv, accr[rr]);
  }
  #pragma unroll
  for (int rr = 0; rr < 8; ++rr) proj16[half * 8 + rr][j] = accr[rr];
  __syncthreads();
  if (tid == 0) {
    float m = ws[WS_G + wtop];
    for (int k = 1; k < KW; ++k) m = fmaxf(m, ws[WS_G + wtop + k]);
    float e[KW], s = 0.f;
    for (int k = 0; k < KW; ++k) { e[k] = expf(ws[WS_G + wtop + k] - m); s += e[k]; }
    for (int k = 0; k < KW; ++k) attn[k] = e[k] / s;
  }
  __syncthreads();
  if (tid < D_PROJ) {
    float a = ws[WS_REACT + tid];
    #pragma unroll
    for (int k = 0; k < KW; ++k) a = fmaf(attn[k], proj16[k][tid], a);
    ts[tid] = a;
  }
  __syncthreads();
  {
    float pa = 0.f, sa = 0.f;
    #pragma unroll 8
    for (int jj = 0; jj < D_PROJ; ++jj) {
      float t = ts[jj];
      pa = fmaf(t, prot_out[jj * D_PROT + tid], pa);
      sa = fmaf(t, sub_out[jj * D_SUB + tid], sa);
    }
    pdelta[tid] = pa; sdelta[tid] = sa;
  }
  __syncthreads();
  for (int i = tid; i < KW * D_PROT; i += 256) {
    int rr = i >> 8, dd = i & 255;
    out[(wtop + rr) * D_PROT + dd] = aprot[rr][dd] + pdelta[dd];
  }
  for (int i = 0; i < N_INT; ++i) {
    int idx = sidx[i];
    out[OUT_SUB + idx * D_SUB + tid] = sub_node[idx * D_SUB + tid] + sdelta[tid];
  }
}

extern "C" void kernel_launch(void* const* d_in, const int* in_sizes, int n_in,
                              void* d_out, int out_size, void* d_ws, size_t ws_size,
                              hipStream_t stream) {
  const float* prot     = (const float*)d_in[0];
  const float* sub      = (const float*)d_in[1];
  const int*   idx      = (const int*)d_in[2];
  const float* Wp       = (const float*)d_in[3];
  const float* bp       = (const float*)d_in[4];
  const float* Ws       = (const float*)d_in[5];
  const float* bs       = (const float*)d_in[6];
  const float* wa       = (const float*)d_in[7];
  // d_in[8] = ba unused (cancels in softmax); wa[128:] unused (constant in g)
  const float* sub_out  = (const float*)d_in[9];
  const float* prot_out = (const float*)d_in[10];
  float* out = (float*)d_out;
  float* ws  = (float*)d_ws;

  void* args[] = {(void*)&prot, (void*)&sub, (void*)&idx, (void*)&Wp,
                  (void*)&bp,   (void*)&Ws,  (void*)&bs,  (void*)&wa,
                  (void*)&sub_out, (void*)&prot_out, (void*)&out, (void*)&ws};
  hipError_t e = hipLaunchCooperativeKernel((const void*)k_all, dim3(NBLK),
                                            dim3(256), args, 0, stream);
  if (e != hipSuccess) {
    k_prep<<<2, 256, 0, stream>>>(sub, idx, Ws, bs, Wp, wa, ws);
    k_rows<<<PB + SB, 256, 0, stream>>>(prot, sub, idx, out, ws);
    k_window<<<WBLK, 256, 0, stream>>>(ws, (unsigned long long*)ws);
    k_final<<<1, 256, 0, stream>>>(prot, sub, idx, Wp, bp, sub_out, prot_out, ws, out);
  }
}

// Round 4
// 187.388 us; speedup vs baseline: 2.0938x; 2.0938x over previous
//
#include <hip/hip_runtime.h>
#include <math.h>

#define N_PROT 50000
#define N_SUB  2000
#define D_PROT 256
#define D_SUB  256
#define D_PROJ 128
#define KW     16
#define N_INT  64
#define NWIN   (N_PROT - KW + 1)

// output layout (floats)
#define OUT_SUB (N_PROT * D_PROT)                 // 12,800,000
#define OUT_IDX (OUT_SUB + N_SUB * D_SUB)         // 13,312,000

// ws layout (floats)
#define WS_PACK  0                                // [0..1] packed argmax u64
#define WS_REACT 2                                // [2..129] reaction
#define WS_CNT   130                              // done-counter (uint)
#define WS_G     644                              // g[N_PROT] (no constant term)
#define WS_P     (WS_G + N_PROT)                  // P[N_PROT] (no constant term)

#define PB 782                                    // prot blocks: 782*64 >= 50000 rows
#define SB 8                                      // sub-copy blocks
#define NBLK (PB + SB + 1)                        // +1 reaction/init block
#define WBLK ((NWIN + 255) / 256)                 // 196 window blocks

// =================== K_A: prep(per-block) + stream + reaction ================
__global__ __launch_bounds__(256) void k_main(
    const float* __restrict__ prot, const float* __restrict__ sub_node,
    const int* __restrict__ int_index, const float* __restrict__ Wp,
    const float* __restrict__ Ws, const float* __restrict__ bs,
    const float* __restrict__ wa, float* __restrict__ out,
    float* __restrict__ ws) {
  const int tid = threadIdx.x, lane = tid & 63, wave = tid >> 6;
  const int b = blockIdx.x;
  if (b < PB) {
    __shared__ float su1[D_PROT], su2[D_PROT];
    __shared__ float swa[D_PROJ];
    // per-block u1 = Wp@w1, u2 = Wp@ones (Wp 128 KB, L2/L3-resident)
    if (tid < D_PROJ) swa[tid] = wa[tid];
    __syncthreads();
    {
      float s1 = 0.f, s2 = 0.f;
      const float4* wrow = (const float4*)&Wp[tid * D_PROJ];
      #pragma unroll 8
      for (int j4 = 0; j4 < D_PROJ / 4; ++j4) {
        float4 w = wrow[j4];
        float4 a = *(const float4*)&swa[j4 * 4];
        s1 = fmaf(w.x, a.x, fmaf(w.y, a.y, fmaf(w.z, a.z, fmaf(w.w, a.w, s1))));
        s2 += w.x + w.y + w.z + w.w;
      }
      su1[tid] = s1; su2[tid] = s2;
    }
    __syncthreads();
    const float4 c1 = *(const float4*)&su1[lane * 4];
    const float4 c2 = *(const float4*)&su2[lane * 4];
    const int rbase = b * 64 + wave * 16;
    if (rbase + 16 <= N_PROT) {
      #pragma unroll 4
      for (int i = 0; i < 16; ++i) {
        const int r = rbase + i;
        const float4 av = *(const float4*)&prot[r * D_PROT + lane * 4];
        *(float4*)&out[r * D_PROT + lane * 4] = av;
        float g = av.x * c1.x + av.y * c1.y + av.z * c1.z + av.w * c1.w;
        float p = av.x * c2.x + av.y * c2.y + av.z * c2.z + av.w * c2.w;
        #pragma unroll
        for (int off = 32; off > 0; off >>= 1) {
          g += __shfl_xor(g, off, 64);
          p += __shfl_xor(p, off, 64);
        }
        if (lane == 0) { ws[WS_G + r] = g; ws[WS_P + r] = p; }
      }
    } else {
      for (int i = 0; i < 16; ++i) {
        const int r = rbase + i;
        if (r >= N_PROT) break;
        const float4 av = *(const float4*)&prot[r * D_PROT + lane * 4];
        *(float4*)&out[r * D_PROT + lane * 4] = av;
        float g = av.x * c1.x + av.y * c1.y + av.z * c1.z + av.w * c1.w;
        float p = av.x * c2.x + av.y * c2.y + av.z * c2.z + av.w * c2.w;
        for (int off = 32; off > 0; off >>= 1) {
          g += __shfl_xor(g, off, 64);
          p += __shfl_xor(p, off, 64);
        }
        if (lane == 0) { ws[WS_G + r] = g; ws[WS_P + r] = p; }
      }
    }
  } else if (b < PB + SB) {
    const int sb = b - PB;
    #pragma unroll 4
    for (int i = tid; i < 16000; i += 256) {
      const int gi = sb * 16000 + i;
      *(float4*)&out[OUT_SUB + gi * 4] = *(const float4*)&sub_node[gi * 4];
    }
    if (sb == 0 && tid < N_INT) out[OUT_IDX + tid] = (float)int_index[tid];
  } else {
    // reaction + init packed argmax + done-counter
    __shared__ int   ridx[N_INT];
    __shared__ float ssum[D_SUB];
    if (tid < N_INT) ridx[tid] = int_index[tid];
    __syncthreads();
    float acc = 0.f;
    #pragma unroll 8
    for (int i = 0; i < N_INT; ++i) acc += sub_node[ridx[i] * D_SUB + tid];
    ssum[tid] = acc;
    __syncthreads();
    if (tid < D_PROJ) {
      float r = 64.0f * bs[tid];
      #pragma unroll 8
      for (int d = 0; d < D_SUB; ++d) r = fmaf(ssum[d], Ws[d * D_PROJ + tid], r);
      ws[WS_REACT + tid] = r;
    }
    if (tid == 0) {
      *((unsigned long long*)ws) = 0ull;          // WS_PACK
      ((unsigned int*)ws)[WS_CNT] = 0u;           // done-counter
    }
  }
}

// =================== K_B: window argmax + last-block patch ===================
__global__ __launch_bounds__(256) void k_finish(
    const float* __restrict__ prot, const float* __restrict__ sub_node,
    const int* __restrict__ int_index, const float* __restrict__ Wp,
    const float* __restrict__ bp, const float* __restrict__ sub_out,
    const float* __restrict__ prot_out, float* __restrict__ ws,
    float* __restrict__ out) {
  __shared__ float sg[256 + KW], sp[256 + KW];
  __shared__ unsigned long long wred[4];
  __shared__ int slast;
  const int tid = threadIdx.x;
  const int w0 = blockIdx.x * 256;
  for (int i = tid; i < 256 + KW - 1; i += 256) {
    int idx = w0 + i;
    bool ok = idx < N_PROT;
    sg[i] = ok ? ws[WS_G + idx] : -1e30f;
    sp[i] = ok ? ws[WS_P + idx] : 0.f;
  }
  __syncthreads();
  {
    int w = w0 + tid;
    unsigned long long best = 0ull;
    if (w < NWIN) {
      float m = sg[tid];
      #pragma unroll
      for (int k = 1; k < KW; ++k) m = fmaxf(m, sg[tid + k]);
      float s = 0.f, t = 0.f;
      #pragma unroll
      for (int k = 0; k < KW; ++k) {
        float e = expf(sg[tid + k] - m);
        s += e;
        t = fmaf(e, sp[tid + k], t);
      }
      t /= s;   // + const dropped: argmax-invariant
      unsigned int bb = __float_as_uint(t);
      unsigned int u = bb ^ ((bb & 0x80000000u) ? 0xFFFFFFFFu : 0x80000000u);
      best = ((unsigned long long)u << 32) |
             (unsigned long long)(0xFFFFFFFFu - (unsigned)w);
    }
    #pragma unroll
    for (int off = 32; off > 0; off >>= 1) {
      unsigned long long o = __shfl_xor(best, off, 64);
      if (o > best) best = o;
    }
    if ((tid & 63) == 0) wred[tid >> 6] = best;
  }
  __syncthreads();
  if (tid == 0) {
    unsigned long long b2 = wred[0];
    for (int i = 1; i < 4; ++i) if (wred[i] > b2) b2 = wred[i];
    atomicMax((unsigned long long*)ws, b2);
    __threadfence();                               // release my atomicMax
    unsigned int ticket = atomicAdd(&((unsigned int*)ws)[WS_CNT], 1u);
    slast = (ticket == WBLK - 1) ? 1 : 0;
  }
  __syncthreads();
  if (!slast) return;

  // -------- last block: all 196 atomicMax's are globally visible -------------
  __shared__ float aprot[KW][D_PROT];
  __shared__ float proj16[KW][D_PROJ];
  __shared__ float attn[KW];
  __shared__ float ts[D_PROJ];
  __shared__ float pdelta[D_PROT], sdelta[D_SUB];
  __shared__ int   sidx[N_INT];
  __shared__ int   swtop;
  if (tid == 0) {
    unsigned long long pk = atomicMax((unsigned long long*)ws, 0ull); // coherent read
    swtop = (int)(0xFFFFFFFFu - (unsigned)(pk & 0xFFFFFFFFull));
  }
  __syncthreads();
  const int wtop = swtop;
  if (tid < N_INT) sidx[tid] = int_index[tid];
  for (int i = tid; i < KW * D_PROT; i += 256) {
    int rr = i >> 8, dd = i & 255;
    aprot[rr][dd] = prot[(wtop + rr) * D_PROT + dd];
  }
  __syncthreads();
  // recompute proj (f32, same math as reference) for the 16 window rows
  const int j = tid & 127, half = tid >> 7;
  float accr[8];
  #pragma unroll
  for (int rr = 0; rr < 8; ++rr) accr[rr] = bp[j];
  for (int k = 0; k < D_PROT; ++k) {
    float wv = Wp[k * D_PROJ + j];
    #pragma unroll
    for (int rr = 0; rr < 8; ++rr)
      accr[rr] = fmaf(aprot[half * 8 + rr][k], wv, accr[rr]);
  }
  #pragma unroll
  for (int rr = 0; rr < 8; ++rr) proj16[half * 8 + rr][j] = accr[rr];
  __syncthreads();
  if (tid == 0) {   // softmax over g window (shift-invariant vs ref)
    float m = ws[WS_G + wtop];
    for (int k = 1; k < KW; ++k) m = fmaxf(m, ws[WS_G + wtop + k]);
    float e[KW], s = 0.f;
    for (int k = 0; k < KW; ++k) { e[k] = expf(ws[WS_G + wtop + k] - m); s += e[k]; }
    for (int k = 0; k < KW; ++k) attn[k] = e[k] / s;
  }
  __syncthreads();
  if (tid < D_PROJ) {
    float a = ws[WS_REACT + tid];
    #pragma unroll
    for (int k = 0; k < KW; ++k) a = fmaf(attn[k], proj16[k][tid], a);
    ts[tid] = a;
  }
  __syncthreads();
  {
    float pa = 0.f, sa = 0.f;
    #pragma unroll 8
    for (int jj = 0; jj < D_PROJ; ++jj) {
      float t = ts[jj];
      pa = fmaf(t, prot_out[jj * D_PROT + tid], pa);
      sa = fmaf(t, sub_out[jj * D_SUB + tid], sa);
    }
    pdelta[tid] = pa; sdelta[tid] = sa;
  }
  __syncthreads();
  for (int i = tid; i < KW * D_PROT; i += 256) {
    int rr = i >> 8, dd = i & 255;
    out[(wtop + rr) * D_PROT + dd] = aprot[rr][dd] + pdelta[dd];
  }
  for (int i = 0; i < N_INT; ++i) {   // duplicates: same value, set-safe
    int idx = sidx[i];
    out[OUT_SUB + idx * D_SUB + tid] = sub_node[idx * D_SUB + tid] + sdelta[tid];
  }
}

extern "C" void kernel_launch(void* const* d_in, const int* in_sizes, int n_in,
                              void* d_out, int out_size, void* d_ws, size_t ws_size,
                              hipStream_t stream) {
  const float* prot     = (const float*)d_in[0];
  const float* sub      = (const float*)d_in[1];
  const int*   idx      = (const int*)d_in[2];
  const float* Wp       = (const float*)d_in[3];
  const float* bp       = (const float*)d_in[4];
  const float* Ws       = (const float*)d_in[5];
  const float* bs       = (const float*)d_in[6];
  const float* wa       = (const float*)d_in[7];
  // d_in[8] = ba unused (cancels in softmax); wa[128:] unused (constant in g)
  const float* sub_out  = (const float*)d_in[9];
  const float* prot_out = (const float*)d_in[10];
  float* out = (float*)d_out;
  float* ws  = (float*)d_ws;

  k_main<<<NBLK, 256, 0, stream>>>(prot, sub, idx, Wp, Ws, bs, wa, out, ws);
  k_finish<<<WBLK, 256, 0, stream>>>(prot, sub, idx, Wp, bp, sub_out, prot_out,
                                     ws, out);
}

// Round 5
// 177.989 us; speedup vs baseline: 2.2043x; 1.0528x over previous
//
#include <hip/hip_runtime.h>
#include <math.h>

#define N_PROT 50000
#define N_SUB  2000
#define D_PROT 256
#define D_SUB  256
#define D_PROJ 128
#define KW     16
#define N_INT  64
#define NWIN   (N_PROT - KW + 1)

// output layout (floats)
#define OUT_SUB (N_PROT * D_PROT)                 // 12,800,000
#define OUT_IDX (OUT_SUB + N_SUB * D_SUB)         // 13,312,000

// ws layout (floats)
#define WS_PACK  0                                // [0..1] packed argmax u64
#define WS_REACT 2                                // [2..129] reaction
#define WS_CNT   130                              // done-counter (uint)
#define WS_U1    132                              // u1 = Wp @ w1 (256)
#define WS_U2    388                              // u2 = Wp @ ones (256)
#define WS_G     644                              // g[N_PROT] (no constant term)
#define WS_P     (WS_G + N_PROT)                  // P[N_PROT] (no constant term)

#define PB 1563                                   // 1563*32 = 50016 >= 50000 rows
#define SB 64                                     // sub-copy blocks
#define NBLK (PB + SB)
#define WBLK ((NWIN + 255) / 256)                 // 196 window blocks

// =================== K0: reaction + u1/u2 + counters (2 blocks) ==============
__global__ __launch_bounds__(256) void k_prep(
    const float* __restrict__ sub_node, const int* __restrict__ int_index,
    const float* __restrict__ Ws, const float* __restrict__ bs,
    const float* __restrict__ Wp, const float* __restrict__ wa,
    float* __restrict__ ws) {
  const int tid = threadIdx.x;
  if (blockIdx.x == 0) {
    __shared__ int   sidx[N_INT];
    __shared__ float ssum[D_SUB];
    if (tid < N_INT) sidx[tid] = int_index[tid];
    __syncthreads();
    float acc = 0.f;
    #pragma unroll 8
    for (int i = 0; i < N_INT; ++i) acc += sub_node[sidx[i] * D_SUB + tid];
    ssum[tid] = acc;
    __syncthreads();
    if (tid < D_PROJ) {
      float r = 64.0f * bs[tid];
      #pragma unroll 8
      for (int d = 0; d < D_SUB; ++d) r = fmaf(ssum[d], Ws[d * D_PROJ + tid], r);
      ws[WS_REACT + tid] = r;
    }
    if (tid == 0) {
      *((unsigned long long*)ws) = 0ull;          // WS_PACK
      ((unsigned int*)ws)[WS_CNT] = 0u;           // done-counter
    }
  } else {
    // u1[k] = sum_j Wp[k][j] * wa[j];  u2[k] = sum_j Wp[k][j]
    __shared__ float swa[D_PROJ];
    if (tid < D_PROJ) swa[tid] = wa[tid];
    __syncthreads();
    float s1 = 0.f, s2 = 0.f;
    const float4* wrow = (const float4*)&Wp[tid * D_PROJ];
    #pragma unroll 8
    for (int j4 = 0; j4 < D_PROJ / 4; ++j4) {
      float4 w = wrow[j4];
      float4 a = *(const float4*)&swa[j4 * 4];
      s1 = fmaf(w.x, a.x, fmaf(w.y, a.y, fmaf(w.z, a.z, fmaf(w.w, a.w, s1))));
      s2 += w.x + w.y + w.z + w.w;
    }
    ws[WS_U1 + tid] = s1;
    ws[WS_U2 + tid] = s2;
  }
}

// =================== K1: stream prot->out + g/P; sub-copy ====================
__global__ __launch_bounds__(256) void k_main(
    const float* __restrict__ prot, const float* __restrict__ sub_node,
    const int* __restrict__ int_index, float* __restrict__ out,
    float* __restrict__ ws) {
  const int tid = threadIdx.x, lane = tid & 63, wave = tid >> 6;
  const int b = blockIdx.x;
  if (b < PB) {
    const float4 c1 = *(const float4*)&ws[WS_U1 + lane * 4];
    const float4 c2 = *(const float4*)&ws[WS_U2 + lane * 4];
    const int rbase = b * 32 + wave * 8;
    if (rbase + 8 <= N_PROT) {
      float4 av[8];
      #pragma unroll
      for (int i = 0; i < 8; ++i)
        av[i] = *(const float4*)&prot[(rbase + i) * D_PROT + lane * 4];
      #pragma unroll
      for (int i = 0; i < 8; ++i)
        *(float4*)&out[(rbase + i) * D_PROT + lane * 4] = av[i];
      #pragma unroll
      for (int i = 0; i < 8; ++i) {
        float g = av[i].x * c1.x + av[i].y * c1.y + av[i].z * c1.z + av[i].w * c1.w;
        float p = av[i].x * c2.x + av[i].y * c2.y + av[i].z * c2.z + av[i].w * c2.w;
        #pragma unroll
        for (int off = 32; off > 0; off >>= 1) {
          g += __shfl_xor(g, off, 64);
          p += __shfl_xor(p, off, 64);
        }
        if (lane == 0) {
          const int r = rbase + i;
          ws[WS_G + r] = g; ws[WS_P + r] = p;
        }
      }
    } else {
      for (int i = 0; i < 8; ++i) {
        const int r = rbase + i;
        if (r >= N_PROT) break;
        const float4 av = *(const float4*)&prot[r * D_PROT + lane * 4];
        *(float4*)&out[r * D_PROT + lane * 4] = av;
        float g = av.x * c1.x + av.y * c1.y + av.z * c1.z + av.w * c1.w;
        float p = av.x * c2.x + av.y * c2.y + av.z * c2.z + av.w * c2.w;
        for (int off = 32; off > 0; off >>= 1) {
          g += __shfl_xor(g, off, 64);
          p += __shfl_xor(p, off, 64);
        }
        if (lane == 0) { ws[WS_G + r] = g; ws[WS_P + r] = p; }
      }
    }
  } else {
    const int sb = b - PB;                        // 64 blocks, 2048 float4 each
    #pragma unroll
    for (int i = 0; i < 8; ++i) {
      const int gi = sb * 2048 + i * 256 + tid;
      if (gi < (N_SUB * D_SUB) / 4)
        *(float4*)&out[OUT_SUB + gi * 4] = *(const float4*)&sub_node[gi * 4];
    }
    if (sb == 0 && tid < N_INT) out[OUT_IDX + tid] = (float)int_index[tid];
  }
}

// =================== K2: window argmax + last-block patch ====================
__global__ __launch_bounds__(256) void k_finish(
    const float* __restrict__ prot, const float* __restrict__ sub_node,
    const int* __restrict__ int_index, const float* __restrict__ Wp,
    const float* __restrict__ bp, const float* __restrict__ sub_out,
    const float* __restrict__ prot_out, float* __restrict__ ws,
    float* __restrict__ out) {
  __shared__ float sg[256 + KW], sp[256 + KW];
  __shared__ unsigned long long wred[4];
  __shared__ int slast;
  const int tid = threadIdx.x;
  const int w0 = blockIdx.x * 256;
  for (int i = tid; i < 256 + KW - 1; i += 256) {
    int idx = w0 + i;
    bool ok = idx < N_PROT;
    sg[i] = ok ? ws[WS_G + idx] : -1e30f;
    sp[i] = ok ? ws[WS_P + idx] : 0.f;
  }
  __syncthreads();
  {
    int w = w0 + tid;
    unsigned long long best = 0ull;
    if (w < NWIN) {
      float m = sg[tid];
      #pragma unroll
      for (int k = 1; k < KW; ++k) m = fmaxf(m, sg[tid + k]);
      float s = 0.f, t = 0.f;
      #pragma unroll
      for (int k = 0; k < KW; ++k) {
        float e = expf(sg[tid + k] - m);
        s += e;
        t = fmaf(e, sp[tid + k], t);
      }
      t /= s;   // + const dropped: argmax-invariant
      unsigned int bb = __float_as_uint(t);
      unsigned int u = bb ^ ((bb & 0x80000000u) ? 0xFFFFFFFFu : 0x80000000u);
      best = ((unsigned long long)u << 32) |
             (unsigned long long)(0xFFFFFFFFu - (unsigned)w);
    }
    #pragma unroll
    for (int off = 32; off > 0; off >>= 1) {
      unsigned long long o = __shfl_xor(best, off, 64);
      if (o > best) best = o;
    }
    if ((tid & 63) == 0) wred[tid >> 6] = best;
  }
  __syncthreads();
  if (tid == 0) {
    unsigned long long b2 = wred[0];
    for (int i = 1; i < 4; ++i) if (wred[i] > b2) b2 = wred[i];
    atomicMax((unsigned long long*)ws, b2);
    __threadfence();                               // release my atomicMax
    unsigned int ticket = atomicAdd(&((unsigned int*)ws)[WS_CNT], 1u);
    slast = (ticket == WBLK - 1) ? 1 : 0;
  }
  __syncthreads();
  if (!slast) return;

  // -------- last block: all atomicMax's globally visible ---------------------
  __shared__ float aprot[KW][D_PROT];
  __shared__ float proj16[KW][D_PROJ];
  __shared__ float attn[KW];
  __shared__ float ts[D_PROJ];
  __shared__ float pdelta[D_PROT], sdelta[D_SUB];
  __shared__ int   sidx[N_INT];
  __shared__ int   swtop;
  if (tid == 0) {
    unsigned long long pk = atomicMax((unsigned long long*)ws, 0ull);
    swtop = (int)(0xFFFFFFFFu - (unsigned)(pk & 0xFFFFFFFFull));
  }
  __syncthreads();
  const int wtop = swtop;
  if (tid < N_INT) sidx[tid] = int_index[tid];
  for (int i = tid; i < KW * D_PROT; i += 256) {
    int rr = i >> 8, dd = i & 255;
    aprot[rr][dd] = prot[(wtop + rr) * D_PROT + dd];
  }
  __syncthreads();
  // recompute proj (f32, same math as reference) for the 16 window rows
  const int j = tid & 127, half = tid >> 7;
  float accr[8];
  #pragma unroll
  for (int rr = 0; rr < 8; ++rr) accr[rr] = bp[j];
  for (int k = 0; k < D_PROT; ++k) {
    float wv = Wp[k * D_PROJ + j];
    #pragma unroll
    for (int rr = 0; rr < 8; ++rr)
      accr[rr] = fmaf(aprot[half * 8 + rr][k], wv, accr[rr]);
  }
  #pragma unroll
  for (int rr = 0; rr < 8; ++rr) proj16[half * 8 + rr][j] = accr[rr];
  __syncthreads();
  if (tid == 0) {   // softmax over g window (shift-invariant vs ref)
    float m = ws[WS_G + wtop];
    for (int k = 1; k < KW; ++k) m = fmaxf(m, ws[WS_G + wtop + k]);
    float e[KW], s = 0.f;
    for (int k = 0; k < KW; ++k) { e[k] = expf(ws[WS_G + wtop + k] - m); s += e[k]; }
    for (int k = 0; k < KW; ++k) attn[k] = e[k] / s;
  }
  __syncthreads();
  if (tid < D_PROJ) {
    float a = ws[WS_REACT + tid];
    #pragma unroll
    for (int k = 0; k < KW; ++k) a = fmaf(attn[k], proj16[k][tid], a);
    ts[tid] = a;
  }
  __syncthreads();
  {
    float pa = 0.f, sa = 0.f;
    #pragma unroll 8
    for (int jj = 0; jj < D_PROJ; ++jj) {
      float t = ts[jj];
      pa = fmaf(t, prot_out[jj * D_PROT + tid], pa);
      sa = fmaf(t, sub_out[jj * D_SUB + tid], sa);
    }
    pdelta[tid] = pa; sdelta[tid] = sa;
  }
  __syncthreads();
  for (int i = tid; i < KW * D_PROT; i += 256) {
    int rr = i >> 8, dd = i & 255;
    out[(wtop + rr) * D_PROT + dd] = aprot[rr][dd] + pdelta[dd];
  }
  for (int i = 0; i < N_INT; ++i) {   // duplicates: same value, set-safe
    int idx = sidx[i];
    out[OUT_SUB + idx * D_SUB + tid] = sub_node[idx * D_SUB + tid] + sdelta[tid];
  }
}

extern "C" void kernel_launch(void* const* d_in, const int* in_sizes, int n_in,
                              void* d_out, int out_size, void* d_ws, size_t ws_size,
                              hipStream_t stream) {
  const float* prot     = (const float*)d_in[0];
  const float* sub      = (const float*)d_in[1];
  const int*   idx      = (const int*)d_in[2];
  const float* Wp       = (const float*)d_in[3];
  const float* bp       = (const float*)d_in[4];
  const float* Ws       = (const float*)d_in[5];
  const float* bs       = (const float*)d_in[6];
  const float* wa       = (const float*)d_in[7];
  // d_in[8] = ba unused (cancels in softmax); wa[128:] unused (constant in g)
  const float* sub_out  = (const float*)d_in[9];
  const float* prot_out = (const float*)d_in[10];
  float* out = (float*)d_out;
  float* ws  = (float*)d_ws;

  k_prep<<<2, 256, 0, stream>>>(sub, idx, Ws, bs, Wp, wa, ws);
  k_main<<<NBLK, 256, 0, stream>>>(prot, sub, idx, out, ws);
  k_finish<<<WBLK, 256, 0, stream>>>(prot, sub, idx, Wp, bp, sub_out, prot_out,
                                     ws, out);
}

// Round 6
// 151.254 us; speedup vs baseline: 2.5940x; 1.1768x over previous
//
#include <hip/hip_runtime.h>
#include <math.h>

#define N_PROT 50000
#define N_SUB  2000
#define D_PROT 256
#define D_SUB  256
#define D_PROJ 128
#define KW     16
#define N_INT  64
#define NWIN   (N_PROT - KW + 1)

// output layout (floats)
#define OUT_SUB (N_PROT * D_PROT)                 // 12,800,000
#define OUT_IDX (OUT_SUB + N_SUB * D_SUB)         // 13,312,000

// ws layout (floats)
#define WS_PACK  0                                // [0..1] packed argmax u64
#define WS_REACT 2                                // [2..129] reaction
#define WS_CNT   130                              // done-counter (uint)
#define WS_U1    132                              // u1 = Wp @ w1 (256)
#define WS_U2    388                              // u2 = Wp @ ones (256)
#define WS_G     644                              // g[N_PROT] (no constant term)
#define WS_P     (WS_G + N_PROT)                  // P[N_PROT] (no constant term)

#define PB 1563                                   // 1563*32 = 50016 >= 50000 rows
#define SB 64                                     // sub-copy blocks
#define NBLK (PB + SB)
#define WBLK ((NWIN + 1023) / 1024)               // 49 window blocks (1024 thr)

// =================== K0: reaction + u1/u2 + counters (2 blocks) ==============
__global__ __launch_bounds__(256) void k_prep(
    const float* __restrict__ sub_node, const int* __restrict__ int_index,
    const float* __restrict__ Ws, const float* __restrict__ bs,
    const float* __restrict__ Wp, const float* __restrict__ wa,
    float* __restrict__ ws) {
  const int tid = threadIdx.x;
  if (blockIdx.x == 0) {
    __shared__ int   sidx[N_INT];
    __shared__ float ssum[D_SUB];
    if (tid < N_INT) sidx[tid] = int_index[tid];
    __syncthreads();
    float acc = 0.f;
    #pragma unroll 8
    for (int i = 0; i < N_INT; ++i) acc += sub_node[sidx[i] * D_SUB + tid];
    ssum[tid] = acc;
    __syncthreads();
    if (tid < D_PROJ) {
      float r = 64.0f * bs[tid];
      #pragma unroll 8
      for (int d = 0; d < D_SUB; ++d) r = fmaf(ssum[d], Ws[d * D_PROJ + tid], r);
      ws[WS_REACT + tid] = r;
    }
    if (tid == 0) {
      *((unsigned long long*)ws) = 0ull;          // WS_PACK
      ((unsigned int*)ws)[WS_CNT] = 0u;           // done-counter
    }
  } else {
    // u1[k] = sum_j Wp[k][j] * wa[j];  u2[k] = sum_j Wp[k][j]
    __shared__ float swa[D_PROJ];
    if (tid < D_PROJ) swa[tid] = wa[tid];
    __syncthreads();
    float s1 = 0.f, s2 = 0.f;
    const float4* wrow = (const float4*)&Wp[tid * D_PROJ];
    #pragma unroll 8
    for (int j4 = 0; j4 < D_PROJ / 4; ++j4) {
      float4 w = wrow[j4];
      float4 a = *(const float4*)&swa[j4 * 4];
      s1 = fmaf(w.x, a.x, fmaf(w.y, a.y, fmaf(w.z, a.z, fmaf(w.w, a.w, s1))));
      s2 += w.x + w.y + w.z + w.w;
    }
    ws[WS_U1 + tid] = s1;
    ws[WS_U2 + tid] = s2;
  }
}

// =================== K1: stream prot->out + g/P; sub-copy ====================
__global__ __launch_bounds__(256) void k_main(
    const float* __restrict__ prot, const float* __restrict__ sub_node,
    const int* __restrict__ int_index, float* __restrict__ out,
    float* __restrict__ ws) {
  const int tid = threadIdx.x, lane = tid & 63, wave = tid >> 6;
  const int b = blockIdx.x;
  if (b < PB) {
    const float4 c1 = *(const float4*)&ws[WS_U1 + lane * 4];
    const float4 c2 = *(const float4*)&ws[WS_U2 + lane * 4];
    const int rbase = b * 32 + wave * 8;
    if (rbase + 8 <= N_PROT) {
      float4 av[8];
      #pragma unroll
      for (int i = 0; i < 8; ++i)
        av[i] = *(const float4*)&prot[(rbase + i) * D_PROT + lane * 4];
      #pragma unroll
      for (int i = 0; i < 8; ++i)
        *(float4*)&out[(rbase + i) * D_PROT + lane * 4] = av[i];
      #pragma unroll
      for (int i = 0; i < 8; ++i) {
        float g = av[i].x * c1.x + av[i].y * c1.y + av[i].z * c1.z + av[i].w * c1.w;
        float p = av[i].x * c2.x + av[i].y * c2.y + av[i].z * c2.z + av[i].w * c2.w;
        #pragma unroll
        for (int off = 32; off > 0; off >>= 1) {
          g += __shfl_xor(g, off, 64);
          p += __shfl_xor(p, off, 64);
        }
        if (lane == 0) {
          const int r = rbase + i;
          ws[WS_G + r] = g; ws[WS_P + r] = p;
        }
      }
    } else {
      for (int i = 0; i < 8; ++i) {
        const int r = rbase + i;
        if (r >= N_PROT) break;
        const float4 av = *(const float4*)&prot[r * D_PROT + lane * 4];
        *(float4*)&out[r * D_PROT + lane * 4] = av;
        float g = av.x * c1.x + av.y * c1.y + av.z * c1.z + av.w * c1.w;
        float p = av.x * c2.x + av.y * c2.y + av.z * c2.z + av.w * c2.w;
        for (int off = 32; off > 0; off >>= 1) {
          g += __shfl_xor(g, off, 64);
          p += __shfl_xor(p, off, 64);
        }
        if (lane == 0) { ws[WS_G + r] = g; ws[WS_P + r] = p; }
      }
    }
  } else {
    const int sb = b - PB;                        // 64 blocks, 2048 float4 each
    #pragma unroll
    for (int i = 0; i < 8; ++i) {
      const int gi = sb * 2048 + i * 256 + tid;
      if (gi < (N_SUB * D_SUB) / 4)
        *(float4*)&out[OUT_SUB + gi * 4] = *(const float4*)&sub_node[gi * 4];
    }
    if (sb == 0 && tid < N_INT) out[OUT_IDX + tid] = (float)int_index[tid];
  }
}

// =================== K2: window argmax + last-block parallel patch ===========
__global__ __launch_bounds__(1024) void k_finish(
    const float* __restrict__ prot, const float* __restrict__ sub_node,
    const int* __restrict__ int_index, const float* __restrict__ Wp,
    const float* __restrict__ bp, const float* __restrict__ sub_out,
    const float* __restrict__ prot_out, float* __restrict__ ws,
    float* __restrict__ out) {
  __shared__ float sg[1024 + KW], sp[1024 + KW];
  __shared__ unsigned long long wred[16];
  __shared__ int slast;
  const int tid = threadIdx.x;
  const int w0 = blockIdx.x * 1024;
  for (int i = tid; i < 1024 + KW - 1; i += 1024) {
    int idx = w0 + i;
    bool ok = idx < N_PROT;
    sg[i] = ok ? ws[WS_G + idx] : -1e30f;
    sp[i] = ok ? ws[WS_P + idx] : 0.f;
  }
  __syncthreads();
  {
    int w = w0 + tid;
    unsigned long long best = 0ull;
    if (w < NWIN) {
      float m = sg[tid];
      #pragma unroll
      for (int k = 1; k < KW; ++k) m = fmaxf(m, sg[tid + k]);
      float s = 0.f, t = 0.f;
      #pragma unroll
      for (int k = 0; k < KW; ++k) {
        float e = expf(sg[tid + k] - m);
        s += e;
        t = fmaf(e, sp[tid + k], t);
      }
      t /= s;   // + const dropped: argmax-invariant
      unsigned int bb = __float_as_uint(t);
      unsigned int u = bb ^ ((bb & 0x80000000u) ? 0xFFFFFFFFu : 0x80000000u);
      best = ((unsigned long long)u << 32) |
             (unsigned long long)(0xFFFFFFFFu - (unsigned)w);
    }
    #pragma unroll
    for (int off = 32; off > 0; off >>= 1) {
      unsigned long long o = __shfl_xor(best, off, 64);
      if (o > best) best = o;
    }
    if ((tid & 63) == 0) wred[tid >> 6] = best;
  }
  __syncthreads();
  if (tid == 0) {
    unsigned long long b2 = wred[0];
    for (int i = 1; i < 16; ++i) if (wred[i] > b2) b2 = wred[i];
    atomicMax((unsigned long long*)ws, b2);
    __threadfence();                               // release my atomicMax
    unsigned int ticket = atomicAdd(&((unsigned int*)ws)[WS_CNT], 1u);
    slast = (ticket == WBLK - 1) ? 1 : 0;
  }
  __syncthreads();
  if (!slast) return;

  // -------- last block (1024 thr): all atomicMax's globally visible ----------
  __shared__ float aprot[KW][D_PROT];              // 16 KB
  __shared__ float attn[KW];
  __shared__ float v[D_PROT];                      // attn-weighted window row
  __shared__ float part[8][D_PROJ];                // ts partials
  __shared__ float ts[D_PROJ];
  __shared__ float partP[4][D_PROT], partS[4][D_PROT];
  __shared__ float pdelta[D_PROT], sdelta[D_SUB];
  __shared__ int   sidx[N_INT];
  __shared__ int   swtop;
  if (tid == 0) {
    unsigned long long pk = atomicMax((unsigned long long*)ws, 0ull);
    swtop = (int)(0xFFFFFFFFu - (unsigned)(pk & 0xFFFFFFFFull));
  }
  __syncthreads();
  const int wtop = swtop;
  {  // load the 16 window rows (1024 float4's, one per thread)
    const int row = tid >> 6, c4 = (tid & 63) * 4;
    *(float4*)&aprot[row][c4] = *(const float4*)&prot[(wtop + row) * D_PROT + c4];
  }
  if (tid < N_INT) sidx[tid] = int_index[tid];
  if (tid == 0) {   // softmax over g window (shift-invariant vs ref)
    float m = ws[WS_G + wtop];
    for (int k = 1; k < KW; ++k) m = fmaxf(m, ws[WS_G + wtop + k]);
    float e[KW], s = 0.f;
    for (int k = 0; k < KW; ++k) { e[k] = expf(ws[WS_G + wtop + k] - m); s += e[k]; }
    for (int k = 0; k < KW; ++k) attn[k] = e[k] / s;
  }
  __syncthreads();
  if (tid < D_PROT) {  // v = attn @ A_window  (exploits sum(attn)=1 for bp term)
    float a = 0.f;
    #pragma unroll
    for (int k = 0; k < KW; ++k) a = fmaf(attn[k], aprot[k][tid], a);
    v[tid] = a;
  }
  __syncthreads();
  {  // ts partials: ts[j] = react[j] + bp[j] + sum_d v[d]*Wp[d][j]
    const int j = tid & 127, s = tid >> 7;        // 8 slices x 32 d
    float p = 0.f;
    const float* wp = Wp + (s * 32) * D_PROJ + j;
    #pragma unroll 8
    for (int d = 0; d < 32; ++d) p = fmaf(v[s * 32 + d], wp[d * D_PROJ], p);
    part[s][j] = p;
  }
  __syncthreads();
  if (tid < D_PROJ) {
    float a = ws[WS_REACT + tid] + bp[tid];
    #pragma unroll
    for (int s = 0; s < 8; ++s) a += part[s][tid];
    ts[tid] = a;
  }
  __syncthreads();
  {  // pdelta/sdelta partials: 4 slices x 32 j each, coalesced over d
    const int d = tid & 255, s = tid >> 8;
    float pp = 0.f, ss = 0.f;
    #pragma unroll 8
    for (int j = 0; j < 32; ++j) {
      const float t = ts[s * 32 + j];
      pp = fmaf(t, prot_out[(s * 32 + j) * D_PROT + d], pp);
      ss = fmaf(t, sub_out[(s * 32 + j) * D_SUB + d], ss);
    }
    partP[s][d] = pp; partS[s][d] = ss;
  }
  __syncthreads();
  if (tid < D_PROT) {
    pdelta[tid] = partP[0][tid] + partP[1][tid] + partP[2][tid] + partP[3][tid];
    sdelta[tid] = partS[0][tid] + partS[1][tid] + partS[2][tid] + partS[3][tid];
  }
  __syncthreads();
  {  // write 16 prot rows
    const int row = tid >> 6, c4 = (tid & 63) * 4;
    float4 a = *(float4*)&aprot[row][c4];
    float4 d = *(float4*)&pdelta[c4];
    a.x += d.x; a.y += d.y; a.z += d.z; a.w += d.w;
    *(float4*)&out[(wtop + row) * D_PROT + c4] = a;
  }
  #pragma unroll
  for (int it = 0; it < 4; ++it) {  // write 64 sub rows (dups: same value)
    const int f = tid + it * 1024;                // 4096 float4 over 64 rows
    const int row = f >> 6, c4 = (f & 63) * 4;
    const int rr = sidx[row];
    float4 sv = *(const float4*)&sub_node[rr * D_SUB + c4];
    float4 d = *(float4*)&sdelta[c4];
    sv.x += d.x; sv.y += d.y; sv.z += d.z; sv.w += d.w;
    *(float4*)&out[OUT_SUB + rr * D_SUB + c4] = sv;
  }
}

extern "C" void kernel_launch(void* const* d_in, const int* in_sizes, int n_in,
                              void* d_out, int out_size, void* d_ws, size_t ws_size,
                              hipStream_t stream) {
  const float* prot     = (const float*)d_in[0];
  const float* sub      = (const float*)d_in[1];
  const int*   idx      = (const int*)d_in[2];
  const float* Wp       = (const float*)d_in[3];
  const float* bp       = (const float*)d_in[4];
  const float* Ws       = (const float*)d_in[5];
  const float* bs       = (const float*)d_in[6];
  const float* wa       = (const float*)d_in[7];
  // d_in[8] = ba unused (cancels in softmax); wa[128:] unused (constant in g)
  const float* sub_out  = (const float*)d_in[9];
  const float* prot_out = (const float*)d_in[10];
  float* out = (float*)d_out;
  float* ws  = (float*)d_ws;

  k_prep<<<2, 256, 0, stream>>>(sub, idx, Ws, bs, Wp, wa, ws);
  k_main<<<NBLK, 256, 0, stream>>>(prot, sub, idx, out, ws);
  k_finish<<<WBLK, 1024, 0, stream>>>(prot, sub, idx, Wp, bp, sub_out, prot_out,
                                      ws, out);
}